// Round 4
// baseline (314.281 us; speedup 1.0000x reference)
//
#include <hip/hip_runtime.h>

// j = 1 - log10(1024*|x-y| + 1), elementwise over float32 tensors.
// N = 33,554,432 f32; traffic 402 MB logical -> ~64 us floor @6.3 TB/s.
// R2: 1 float4/thread gave only 2.5 TB/s HBM (MLP-starved).
// R3: 4 float4/thread + nontemporal stores; failed to compile because
//     __builtin_nontemporal_store rejects HIP_vector_type. R4: use a native
//     clang ext_vector_type(4) float (same layout, legal for the builtin).

typedef float f32x4 __attribute__((ext_vector_type(4)));

#define UNROLL 4
#define BLOCK 256

__device__ __forceinline__ float j_elem(float xv, float yv) {
    float d = xv - yv;
    float dist = 1024.0f * fabsf(d);             // sqrt(1024^2 d^2) = 1024|d|
    return 1.0f - 0.30102999566398120f * __log2f(dist + 1.0f);
}

__device__ __forceinline__ f32x4 j_vec(f32x4 xv, f32x4 yv) {
    f32x4 ov;
    ov.x = j_elem(xv.x, yv.x);
    ov.y = j_elem(xv.y, yv.y);
    ov.z = j_elem(xv.z, yv.z);
    ov.w = j_elem(xv.w, yv.w);
    return ov;
}

__global__ __launch_bounds__(BLOCK) void j_vec4x4_kernel(const f32x4* __restrict__ x,
                                                         const f32x4* __restrict__ y,
                                                         f32x4* __restrict__ out,
                                                         int nvec) {
    int base = blockIdx.x * (BLOCK * UNROLL) + threadIdx.x;

    if (base + (UNROLL - 1) * BLOCK < nvec) {
        // Full tile: issue all 8 loads before any compute (max MLP).
        f32x4 xs[UNROLL], ys[UNROLL];
#pragma unroll
        for (int k = 0; k < UNROLL; ++k) xs[k] = x[base + k * BLOCK];
#pragma unroll
        for (int k = 0; k < UNROLL; ++k) ys[k] = y[base + k * BLOCK];
#pragma unroll
        for (int k = 0; k < UNROLL; ++k) {
            f32x4 ov = j_vec(xs[k], ys[k]);
            __builtin_nontemporal_store(ov, &out[base + k * BLOCK]);
        }
    } else {
        // Tail tile: per-vector guard.
#pragma unroll
        for (int k = 0; k < UNROLL; ++k) {
            int i = base + k * BLOCK;
            if (i < nvec) {
                f32x4 ov = j_vec(x[i], y[i]);
                __builtin_nontemporal_store(ov, &out[i]);
            }
        }
    }
}

__global__ __launch_bounds__(BLOCK) void j_tail_kernel(const float* __restrict__ x,
                                                       const float* __restrict__ y,
                                                       float* __restrict__ out,
                                                       int start, int n) {
    int i = start + blockIdx.x * blockDim.x + threadIdx.x;
    if (i >= n) return;
    out[i] = j_elem(x[i], y[i]);
}

extern "C" void kernel_launch(void* const* d_in, const int* in_sizes, int n_in,
                              void* d_out, int out_size, void* d_ws, size_t ws_size,
                              hipStream_t stream) {
    const int n = out_size;                  // 33,554,432 f32 elements
    const int nvec = n / 4;                  // float4 count (8,388,608)
    const int rem = n - nvec * 4;

    if (nvec > 0) {
        int blocks = (nvec + BLOCK * UNROLL - 1) / (BLOCK * UNROLL);  // 8192
        j_vec4x4_kernel<<<blocks, BLOCK, 0, stream>>>(
            (const f32x4*)d_in[0], (const f32x4*)d_in[1], (f32x4*)d_out, nvec);
    }
    if (rem > 0) {
        j_tail_kernel<<<1, BLOCK, 0, stream>>>(
            (const float*)d_in[0], (const float*)d_in[1],
            (float*)d_out, nvec * 4, n);
    }
}